// Round 26
// baseline (347.247 us; speedup 1.0000x reference)
//
#include <hip/hip_runtime.h>
#include <hip/hip_bf16.h>

#define BB 2
#define HH 256
#define WW 256
#define HW (HH*WW)
#define GP 258              // padded gated dim (1px halo each side)
#define GPP (GP*GP)

typedef __attribute__((ext_vector_type(8))) short bf16x8;
typedef __attribute__((ext_vector_type(4))) float f32x4;

__device__ __forceinline__ float geluf(float x) {
    return 0.5f * x * (1.0f + erff(x * 0.7071067811865475f));
}

__device__ __forceinline__ ushort f2bf(float f) {
    __hip_bfloat16 h = __float2bfloat16(f);
    return *reinterpret_cast<ushort*>(&h);
}
__device__ __forceinline__ float bf2f(ushort u) {
    uint v = ((uint)u) << 16;
    return *reinterpret_cast<float*>(&v);
}

// compact index [0,96) -> actual coordinate (rows/cols = 0,2,6 mod 8)
__device__ __forceinline__ int dec96(int i) {
    int q = i / 3, r = i - q * 3;
    return q * 8 + (r == 0 ? 0 : (r == 1 ? 2 : 6));
}

// x (NCHW fp32, 72ch) -> xt (NHWC bf16, 96ch zero-padded).
__global__ __launch_bounds__(256) void xpose_kernel(
    const float* __restrict__ x, ushort* __restrict__ xt)
{
    const int pix = blockIdx.x * 256 + threadIdx.x;   // [0, BB*HW)
    const int b   = pix >> 16;
    const int rem = pix & 65535;

    uint w[48];
    const float* xb = x + (size_t)b * 72 * HW + rem;
    #pragma unroll
    for (int i = 0; i < 36; ++i) {
        const ushort lo = f2bf(xb[(size_t)(2 * i)     * HW]);
        const ushort hi = f2bf(xb[(size_t)(2 * i + 1) * HW]);
        w[i] = (uint)lo | ((uint)hi << 16);
    }
    #pragma unroll
    for (int i = 36; i < 48; ++i) w[i] = 0;

    uint* dst = reinterpret_cast<uint*>(xt + (size_t)pix * 96);
    #pragma unroll
    for (int k = 0; k < 12; ++k) {
        uint4 u = { w[4*k], w[4*k+1], w[4*k+2], w[4*k+3] };
        *reinterpret_cast<uint4*>(dst + 4 * k) = u;
    }
}

// Prepack fused conv1(64co)+dw1(32co) weights into MFMA A-frag order.
__global__ __launch_bounds__(256) void prepack_w1_kernel(
    const float* __restrict__ conv_w, const float* __restrict__ dw1_w,
    ushort* __restrict__ wpc1)
{
    const int idx = blockIdx.x * 256 + threadIdx.x;   // 9*3*6*64 = 10368
    if (idx >= 9 * 3 * 6 * 64) return;
    const int lane = idx & 63;
    int rest = idx >> 6;
    const int mf = rest % 6; rest /= 6;
    const int cb = rest % 3;
    const int t  = rest / 3;
    const int co  = mf * 16 + (lane & 15);
    const int ci0 = cb * 32 + (lane >> 4) * 8;
    ushort* dst = wpc1 + (size_t)idx * 8;
    #pragma unroll
    for (int j = 0; j < 8; ++j) {
        const int ci = ci0 + j;
        float w = 0.0f;
        if (ci < 72)
            w = (co < 64) ? conv_w[((size_t)co * 72 + ci) * 9 + t]
                          : dw1_w[((size_t)(co - 64) * 72 + ci) * 9 + t];
        dst[j] = f2bf(w);
    }
}

// Fused conv1+dw1 as MFMA implicit GEMM (M=96, K=9*96) over xt.
// relu1 emitted as bf16 NHWC-32 (for the MFMA gate conv).
__global__ __launch_bounds__(256) void conv1dw1_mfma_kernel(
    const ushort* __restrict__ xt, const ushort* __restrict__ wpc1,
    const float* __restrict__ conv_b, const float* __restrict__ dw1_b,
    ushort* __restrict__ fg, ushort* __restrict__ relu1t)
{
    const int lane = threadIdx.x & 63;
    const int wave = threadIdx.x >> 6;
    const int l15  = lane & 15;
    const int lg   = lane >> 4;

    const int bid  = blockIdx.x;          // 1024 = b(2) * y(256) * half(2)
    const int b    = bid >> 9;
    const int rest = bid & 511;
    const int y    = rest >> 1;
    const int x0   = (rest & 1) * 128 + wave * 32;

    f32x4 acc[6][2];
    #pragma unroll
    for (int mf = 0; mf < 6; ++mf)
        #pragma unroll
        for (int nf = 0; nf < 2; ++nf)
            acc[mf][nf] = (f32x4){0.f, 0.f, 0.f, 0.f};

    const bf16x8 zero8 = {};

    #pragma unroll 1
    for (int t = 0; t < 9; ++t) {
        const int dy = t / 3 - 1, dx = t % 3 - 1;
        const int yy = y + dy;
        if ((unsigned)yy >= (unsigned)HH) continue;

        const int xA = x0 + l15 + dx;
        const int xB = xA + 16;
        const bool va = (unsigned)xA < (unsigned)WW;
        const bool vb = (unsigned)xB < (unsigned)WW;
        const int xAc = min(max(xA, 0), WW - 1);
        const int xBc = min(xB, WW - 1);

        const ushort* rowbase = xt + ((size_t)(b * HH + yy) * WW) * 96;
        const ushort* pA = rowbase + (size_t)xAc * 96 + lg * 8;
        const ushort* pB = rowbase + (size_t)xBc * 96 + lg * 8;
        const ushort* wp = wpc1 + (size_t)(t * 3) * (6 * 512) + lane * 8;

        #pragma unroll
        for (int cb = 0; cb < 3; ++cb) {
            bf16x8 B0 = *reinterpret_cast<const bf16x8*>(pA + cb * 32);
            bf16x8 B1 = *reinterpret_cast<const bf16x8*>(pB + cb * 32);
            B0 = va ? B0 : zero8;
            B1 = vb ? B1 : zero8;
            const ushort* wpc = wp + (size_t)cb * (6 * 512);
            #pragma unroll
            for (int mf = 0; mf < 6; ++mf) {
                const bf16x8 A = *reinterpret_cast<const bf16x8*>(wpc + mf * 512);
                acc[mf][0] = __builtin_amdgcn_mfma_f32_16x16x32_bf16(A, B0, acc[mf][0], 0, 0, 0);
                acc[mf][1] = __builtin_amdgcn_mfma_f32_16x16x32_bf16(A, B1, acc[mf][1], 0, 0, 0);
            }
        }
    }

    #pragma unroll
    for (int nf = 0; nf < 2; ++nf) {
        const int xx = x0 + nf * 16 + l15;
        ushort* fgp = fg + ((size_t)(b * HH + y) * WW + xx) * 64;
        #pragma unroll
        for (int mf = 0; mf < 4; ++mf) {
            const int co = mf * 16 + lg * 4;
            ushort pk[4];
            #pragma unroll
            for (int r = 0; r < 4; ++r)
                pk[r] = f2bf(geluf(acc[mf][nf][r] + conv_b[co + r]));
            *reinterpret_cast<uint2*>(fgp + co) = *reinterpret_cast<uint2*>(pk);
        }
    }
    // relu1t epilogue: bf16 NHWC-32
    #pragma unroll
    for (int mf = 4; mf < 6; ++mf) {
        const int co = (mf - 4) * 16 + lg * 4;
        #pragma unroll
        for (int nf = 0; nf < 2; ++nf) {
            const int xx = x0 + nf * 16 + l15;
            ushort pk[4];
            #pragma unroll
            for (int r = 0; r < 4; ++r)
                pk[r] = f2bf(fmaxf(acc[mf][nf][r] + dw1_b[co + r], 0.0f));
            *reinterpret_cast<uint2*>(relu1t + ((size_t)(b * HH + y) * WW + xx) * 32 + co) =
                *reinterpret_cast<uint2*>(pk);
        }
    }
}

// Prepack ddct weights (7 layers) into MFMA A-fragment order.
__global__ __launch_bounds__(256) void prepack_wb_kernel(
    const float* __restrict__ ddct_w, ushort* __restrict__ wpb)
{
    const int idx = blockIdx.x * 256 + threadIdx.x;   // 7*9*2*4*64 = 32256
    if (idx >= 7 * 9 * 2 * 4 * 64) return;
    const int lane = idx & 63;
    int rest = idx >> 6;
    const int mf = rest & 3; rest >>= 2;
    const int cb = rest & 1; rest >>= 1;
    const int t  = rest % 9;
    const int li = rest / 9;
    const int co  = mf * 16 + (lane & 15);
    const int ci0 = cb * 32 + (lane >> 4) * 8;
    ushort* dst = wpb + (size_t)idx * 8;
    #pragma unroll
    for (int j = 0; j < 8; ++j)
        dst[j] = f2bf(ddct_w[(((size_t)li * 64 + co) * 64 + ci0 + j) * 9 + t]);
}

// All 7 branch convs on the compact 96x96 grid as MFMA implicit GEMM.
__global__ __launch_bounds__(256) void branch_mfma_kernel(
    const ushort* __restrict__ fg, const ushort* __restrict__ wpb,
    const float* __restrict__ ddct_b, float* __restrict__ ycomp)
{
    const int lane = threadIdx.x & 63;
    const int wave = threadIdx.x >> 6;
    const int l15  = lane & 15;
    const int lg   = lane >> 4;

    int bid = blockIdx.x;              // (li*BB+b)*72 + t72
    const int t72 = bid % 72; bid /= 72;
    const int b  = bid & 1;
    const int li = bid >> 1;
    const int widx = t72 * 4 + wave;
    const int r  = widx / 3;
    const int c0 = (widx - r * 3) * 32;
    const int R  = dec96(r);

    const int cA = c0 + l15, cB = cA + 16;
    const int CA = dec96(cA), CB2 = dec96(cB);

    f32x4 acc[4][2];
    #pragma unroll
    for (int mf = 0; mf < 4; ++mf)
        #pragma unroll
        for (int nf = 0; nf < 2; ++nf)
            acc[mf][nf] = (f32x4){0.f, 0.f, 0.f, 0.f};

    const bf16x8 zero8 = {};
    const ushort* fgb = fg + (size_t)b * HW * 64;

    #pragma unroll 1
    for (int t = 0; t < 9; ++t) {
        const int dy = t / 3 - 1, dx = t % 3 - 1;
        const int yy = R + dy;
        if ((unsigned)yy >= (unsigned)HH) continue;

        const int xA = CA + dx, xB = CB2 + dx;
        const bool va = (unsigned)xA < (unsigned)WW;
        const bool vb = (unsigned)xB < (unsigned)WW;
        const int xAc = min(max(xA, 0), WW - 1);
        const int xBc = min(max(xB, 0), WW - 1);

        const ushort* rowb = fgb + (size_t)yy * WW * 64;
        const ushort* pA = rowb + (size_t)xAc * 64 + lg * 8;
        const ushort* pB = rowb + (size_t)xBc * 64 + lg * 8;
        const ushort* wp = wpb + (size_t)((li * 9 + t) * 2) * (4 * 512) + lane * 8;

        #pragma unroll
        for (int cb = 0; cb < 2; ++cb) {
            bf16x8 B0 = *reinterpret_cast<const bf16x8*>(pA + cb * 32);
            bf16x8 B1 = *reinterpret_cast<const bf16x8*>(pB + cb * 32);
            B0 = va ? B0 : zero8;
            B1 = vb ? B1 : zero8;
            const ushort* wpc = wp + (size_t)cb * (4 * 512);
            #pragma unroll
            for (int mf = 0; mf < 4; ++mf) {
                const bf16x8 A = *reinterpret_cast<const bf16x8*>(wpc + mf * 512);
                acc[mf][0] = __builtin_amdgcn_mfma_f32_16x16x32_bf16(A, B0, acc[mf][0], 0, 0, 0);
                acc[mf][1] = __builtin_amdgcn_mfma_f32_16x16x32_bf16(A, B1, acc[mf][1], 0, 0, 0);
            }
        }
    }

    #pragma unroll
    for (int nf = 0; nf < 2; ++nf) {
        const int c = c0 + nf * 16 + l15;
        const int C = dec96(c);
        const ushort* res = fgb + ((size_t)R * WW + C) * 64;
        #pragma unroll
        for (int mf = 0; mf < 4; ++mf) {
            const int co = mf * 16 + lg * 4;
            ushort r4[4];
            *reinterpret_cast<uint2*>(r4) = *reinterpret_cast<const uint2*>(res + co);
            #pragma unroll
            for (int rr = 0; rr < 4; ++rr) {
                const float v = geluf(acc[mf][nf][rr] + ddct_b[li * 64 + co + rr]) + bf2f(r4[rr]);
                ycomp[((((size_t)li * BB + b) * 64 + co + rr) * 96 + r) * 96 + c] = v;
            }
        }
    }
}

// Depthwise 3x3 stride 8 dil 2 pad 2 -> 32x32 (DCT->IDCT identity skipped).
__global__ __launch_bounds__(256) void dctc_kernel(
    const float* __restrict__ ycomp, const float* __restrict__ dctc_w,
    const float* __restrict__ dctc_b, float* __restrict__ s_all)
{
    const int idx = blockIdx.x * 256 + threadIdx.x;
    if (idx >= 7 * BB * 64 * 32 * 32) return;
    const int ow = idx & 31;
    const int oh = (idx >> 5) & 31;
    const int c  = (idx >> 10) & 63;
    const int b  = (idx >> 16) & (BB - 1);
    const int li = idx >> 17;

    const float* yc = ycomp + (((size_t)li * BB + b) * 64 + c) * (96 * 96);
    const float* w  = dctc_w + (li * 64 + c) * 9;
    float acc = dctc_b[li * 64 + c];
    #pragma unroll
    for (int ky = 0; ky < 3; ++ky) {
        const int cr = 3 * oh + ky - 1;
        if (cr < 0) continue;
        #pragma unroll
        for (int kx = 0; kx < 3; ++kx) {
            const int cc = 3 * ow + kx - 1;
            if (cc < 0) continue;
            acc = fmaf(yc[cr * 96 + cc], w[ky * 3 + kx], acc);
        }
    }
    s_all[idx] = acc;
}

// Prepack gate weights into MFMA A-frag order:
// wg[(ct*64+lane)*8+j] = dw3_w[ch=ct*16+(lane&15)][k=(lane>>4)*8+j]
__global__ __launch_bounds__(256) void prepack_wg_kernel(
    const float* __restrict__ dw3_w, ushort* __restrict__ wg)
{
    const int idx = blockIdx.x * 256 + threadIdx.x;   // 32*64 = 2048
    if (idx >= 2048) return;
    const int lane = idx & 63;
    const int ct = idx >> 6;
    const int ch = ct * 16 + (lane & 15);
    const int k0 = (lane >> 4) * 8;
    ushort* dst = wg + (size_t)idx * 8;
    #pragma unroll
    for (int j = 0; j < 8; ++j)
        dst[j] = f2bf(dw3_w[(size_t)ch * 32 + k0 + j]);
}

// Zero the 1px halo border of the padded gated tensor.
// Must run AFTER fg/ycomp (aliasing the padded gated region) are dead.
__global__ __launch_bounds__(256) void halo_zero_kernel(ushort* __restrict__ gt)
{
    const int PB = 2 * GP * 64 + 2 * 256 * 64;   // 65792 uint4 per batch
    const int i = blockIdx.x * 256 + threadIdx.x;
    if (i >= BB * PB) return;
    const int b = i / PB;
    int r = i - b * PB;
    size_t px;
    int c4;
    if (r < 2 * GP * 64) {
        const int rr = r / (GP * 64);
        int rem = r - rr * (GP * 64);
        const int xp = rem / 64; c4 = rem % 64;
        px = (size_t)(rr ? GP - 1 : 0) * GP + xp;
    } else {
        r -= 2 * GP * 64;
        const int side = r / (256 * 64);
        int rem = r - side * (256 * 64);
        const int yp = 1 + rem / 64; c4 = rem % 64;
        px = (size_t)yp * GP + (side ? GP - 1 : 0);
    }
    const uint4 z = {0u, 0u, 0u, 0u};
    *reinterpret_cast<uint4*>(gt + ((size_t)b * GPP + px) * 512 + c4 * 8) = z;
}

// Gate 1x1 conv (32->512) on MFMA (K=32 = one mfma_16x16x32), fused with
// sigmoid + bilinear upsample + multiply, writing PADDED NHWC bf16.
__global__ __launch_bounds__(256, 2) void gated_mfma_kernel(
    const ushort* __restrict__ relu1t, const ushort* __restrict__ wg,
    const float* __restrict__ dw3_b, const float* __restrict__ s_all,
    ushort* __restrict__ gt)
{
    __shared__ float nodes[5120];        // [512 ch][10 x-nodes], y-blended
    const int tid  = threadIdx.x;
    const int lane = tid & 63;
    const int wave = tid >> 6;
    const int l15  = lane & 15;
    const int lg   = lane >> 4;

    const int bid = blockIdx.x;          // 2048 = b(2) * y(256) * xq(4)
    const int b  = bid >> 10;
    const int y  = (bid >> 2) & 255;
    const int x0 = (bid & 3) * 64;

    const float sy = (y + 0.5f) * 0.125f - 0.5f;
    const float fy0f = floorf(sy);
    const float fy = sy - fy0f;
    int y0 = (int)fy0f;
    const int y1 = min(y0 + 1, 31);
    y0 = max(y0, 0);
    const int xb = (x0 >> 3) - 1;

    const int lmap[8] = {0, 1, 2, 3, 4, 3, 5, 6};
    #pragma unroll 1
    for (int e = tid; e < 5120; e += 256) {
        const int ch = e / 10, j = e - ch * 10;
        const int li = lmap[ch >> 6];
        const float* sp = s_all + (((size_t)li * BB + b) * 64 + (ch & 63)) * 1024;
        const int xn = min(max(xb + j, 0), 31);
        const float a0 = sp[y0 * 32 + xn], a1 = sp[y1 * 32 + xn];
        nodes[e] = a0 + fy * (a1 - a0);
    }
    __syncthreads();

    // B fragments: 4 px-tiles; K=32 contiguous per px in relu1t
    bf16x8 Bv[4];
    const ushort* rb = relu1t + ((size_t)(b * HH + y) * WW + x0) * 32;
    #pragma unroll
    for (int pxt = 0; pxt < 4; ++pxt)
        Bv[pxt] = *reinterpret_cast<const bf16x8*>(rb + (pxt * 16 + l15) * 32 + lg * 8);

    ushort* gy = gt + (((size_t)b * GPP) + (size_t)(y + 1) * GP + (x0 + 1)) * 512;
    const f32x4 zero4 = {0.f, 0.f, 0.f, 0.f};

    #pragma unroll 1
    for (int i = 0; i < 8; ++i) {
        const int ct = wave * 8 + i;
        const bf16x8 A = *reinterpret_cast<const bf16x8*>(wg + (size_t)(ct * 64 + lane) * 8);
        const int ch0 = ct * 16 + lg * 4;
        const float4 bb = *reinterpret_cast<const float4*>(dw3_b + ch0);
        const float bias4[4] = {bb.x, bb.y, bb.z, bb.w};
        f32x4 acc[4];
        #pragma unroll
        for (int pxt = 0; pxt < 4; ++pxt)
            acc[pxt] = __builtin_amdgcn_mfma_f32_16x16x32_bf16(A, Bv[pxt], zero4, 0, 0, 0);
        #pragma unroll
        for (int pxt = 0; pxt < 4; ++pxt) {
            const int pxl = pxt * 16 + l15;
            const int jl = (pxl + 4) >> 3;
            const float fx = (float)((pxl + 4) & 7) * 0.125f + 0.0625f;
            ushort pk[4];
            #pragma unroll
            for (int r = 0; r < 4; ++r) {
                const int ch = ch0 + r;
                const float g = 1.0f / (1.0f + exp2f(-1.4426950408889634f * (acc[pxt][r] + bias4[r])));
                const float n0v = nodes[ch * 10 + jl];
                const float n1v = nodes[ch * 10 + jl + 1];
                const float v = n0v + fx * (n1v - n0v);
                pk[r] = f2bf(v * g);
            }
            *reinterpret_cast<uint2*>(gy + (size_t)pxl * 512 + ch0) = *reinterpret_cast<uint2*>(pk);
        }
    }
}

// Prepack ar_w into MFMA A-fragment order (bf16), CB-MAJOR for LDS staging:
// wpack[(((cb*9 + t)*5 + mf)*64 + lane)*8 + j]
__global__ __launch_bounds__(256) void prepack_w_kernel(
    const float* __restrict__ ar_w, ushort* __restrict__ wpack)
{
    const int idx = blockIdx.x * 256 + threadIdx.x;   // 16*9*5*64 = 46080
    if (idx >= 16 * 9 * 5 * 64) return;
    const int lane = idx & 63;
    int rest = idx >> 6;
    const int mf = rest % 5; rest /= 5;
    const int t  = rest % 9;
    const int cb = rest / 9;
    const int co  = mf * 16 + (lane & 15);
    const int ci0 = cb * 32 + (lane >> 4) * 8;
    ushort* dst = wpack + (size_t)idx * 8;
    #pragma unroll
    for (int j = 0; j < 8; ++j) {
        const float w = (co < 72) ? ar_w[((size_t)co * 512 + ci0 + j) * 9 + t] : 0.0f;
        dst[j] = f2bf(w);
    }
}

#define WPK_CHUNK (9 * 5 * 512)   // ushorts per cb chunk = 23040 (46080 B)

// Final conv 512->72 as implicit GEMM on MFMA (padded NHWC bf16 input).
// v10 = v9 + B prefetch depth 2 (triple buffer; cross-cb covers next cb's
// taps 0,1). Round-25 model: 1-tap cover (~388cyc) marginal for L2 and
// insufficient for L3 (~600-900cyc) B lines; doubling cover to ~776cyc.
__global__ __launch_bounds__(256, 2) void conv_ar_mfma_kernel(
    const ushort* __restrict__ gt, const ushort* __restrict__ wpack,
    const float* __restrict__ ar_b, float* __restrict__ out)
{
    __shared__ ushort smw[WPK_CHUNK];
    const int tid  = threadIdx.x;
    const int lane = tid & 63;
    const int wave = tid >> 6;
    const int l15  = lane & 15;
    const int lg   = lane >> 4;

    // bijective XCD swizzle: nwg=512, 8 XCDs, 64 logical blocks per XCD
    const int lb = (blockIdx.x & 7) * 64 + (blockIdx.x >> 3);
    const int b  = lb >> 8;
    const int y  = lb & 255;
    const int x0 = wave * 64;

    f32x4 acc[5][4];
    #pragma unroll
    for (int mf = 0; mf < 5; ++mf)
        #pragma unroll
        for (int nf = 0; nf < 4; ++nf)
            acc[mf][nf] = (f32x4){0.f, 0.f, 0.f, 0.f};

    const ushort* rowp[3];
    #pragma unroll
    for (int dy = 0; dy < 3; ++dy)
        rowp[dy] = gt + ((size_t)b * GPP + (size_t)(y + dy) * GP) * 512;
    int off[3][4];
    #pragma unroll
    for (int dx = 0; dx < 3; ++dx)
        #pragma unroll
        for (int nf = 0; nf < 4; ++nf)
            off[dx][nf] = (x0 + nf * 16 + l15 + dx) * 512 + lg * 8;

    // prologue: stage cb=0 into LDS
    uint4 streg[12];
    {
        const uint4* s = reinterpret_cast<const uint4*>(wpack);
        #pragma unroll
        for (int i = 0; i < 12; ++i) {
            const int e = i * 256 + tid;
            streg[i] = (e < 2880) ? s[e] : (uint4){0u, 0u, 0u, 0u};
        }
        uint4* d = reinterpret_cast<uint4*>(smw);
        #pragma unroll
        for (int i = 0; i < 12; ++i) {
            const int e = i * 256 + tid;
            if (e < 2880) d[e] = streg[i];
        }
    }
    __syncthreads();

    // B prologue: (cb=0, t=0) and (cb=0, t=1)
    bf16x8 Bcur[4], Bn1[4], Bn2[4];
    #pragma unroll
    for (int nf = 0; nf < 4; ++nf) {
        Bcur[nf] = *reinterpret_cast<const bf16x8*>(rowp[0] + off[0][nf]);
        Bn1[nf]  = *reinterpret_cast<const bf16x8*>(rowp[0] + off[1][nf]);
    }

    #pragma unroll 1
    for (int cb = 0; cb < 16; ++cb) {
        // T14: issue next cb's stage loads; latency hides under MFMAs
        if (cb < 15) {
            const uint4* s = reinterpret_cast<const uint4*>(
                wpack + (size_t)(cb + 1) * WPK_CHUNK);
            #pragma unroll
            for (int i = 0; i < 12; ++i) {
                const int e = i * 256 + tid;
                if (e < 2880) streg[i] = s[e];
            }
        }

        const int cbo = cb * 32;
        #pragma unroll
        for (int t = 0; t < 9; ++t) {
            // prefetch B for tap t+2 (cross-cb: taps 0,1 of cb+1)
            if (t < 7) {
                const int tp = t + 2;
                const int dyn = tp / 3, dxn = tp % 3;
                #pragma unroll
                for (int nf = 0; nf < 4; ++nf)
                    Bn2[nf] = *reinterpret_cast<const bf16x8*>(
                        rowp[dyn] + off[dxn][nf] + cbo);
            } else if (cb < 15) {
                const int tp = t - 7;              // 0 at t=7, 1 at t=8
                #pragma unroll
                for (int nf = 0; nf < 4; ++nf)
                    Bn2[nf] = *reinterpret_cast<const bf16x8*>(
                        rowp[0] + off[tp][nf] + cbo + 32);
            }
            __builtin_amdgcn_s_setprio(1);
            #pragma unroll
            for (int mf = 0; mf < 5; ++mf) {
                const bf16x8 A = *reinterpret_cast<const bf16x8*>(
                    smw + (t * 5 + mf) * 512 + lane * 8);
                #pragma unroll
                for (int nf = 0; nf < 4; ++nf)
                    acc[mf][nf] = __builtin_amdgcn_mfma_f32_16x16x32_bf16(
                        A, Bcur[nf], acc[mf][nf], 0, 0, 0);
            }
            __builtin_amdgcn_s_setprio(0);
            #pragma unroll
            for (int nf = 0; nf < 4; ++nf) { Bcur[nf] = Bn1[nf]; Bn1[nf] = Bn2[nf]; }
        }

        __syncthreads();           // all waves done reading smw for this cb
        if (cb < 15) {
            uint4* d = reinterpret_cast<uint4*>(smw);
            #pragma unroll
            for (int i = 0; i < 12; ++i) {
                const int e = i * 256 + tid;
                if (e < 2880) d[e] = streg[i];
            }
        }
        __syncthreads();           // next stage visible
    }

    #pragma unroll
    for (int mf = 0; mf < 5; ++mf) {
        const int co = mf * 16 + lg * 4;
        if (co >= 72) continue;
        #pragma unroll
        for (int nf = 0; nf < 4; ++nf) {
            const int x = x0 + nf * 16 + l15;
            float* op = out + (((size_t)(b * 72 + co) * HH + y) * WW) + x;
            #pragma unroll
            for (int r = 0; r < 4; ++r)
                op[(size_t)r * HW] = acc[mf][nf][r] + ar_b[co + r];
        }
    }
}

extern "C" void kernel_launch(void* const* d_in, const int* in_sizes, int n_in,
                              void* d_out, int out_size, void* d_ws, size_t ws_size,
                              hipStream_t stream) {
    const float* x      = (const float*)d_in[0];
    const float* conv_w = (const float*)d_in[1];
    const float* conv_b = (const float*)d_in[2];
    const float* ddct_w = (const float*)d_in[3];
    const float* ddct_b = (const float*)d_in[4];
    const float* dctc_w = (const float*)d_in[5];
    const float* dctc_b = (const float*)d_in[6];
    const float* dw1_w  = (const float*)d_in[7];
    const float* dw1_b  = (const float*)d_in[8];
    const float* dw3_w  = (const float*)d_in[9];
    const float* dw3_b  = (const float*)d_in[10];
    const float* ar_w   = (const float*)d_in[11];
    const float* ar_b   = (const float*)d_in[12];
    float* out = (float*)d_out;

    float* ws = (float*)d_ws;
    // Layout (float slots). gated (padded) spans [0 .. 34,080,768); fg/ycomp
    // alias it (both dead before halo+gated writes — halo_zero runs AFTER dctc).
    ushort* gated_t = (ushort*)ws;               // [0 .. 34,080,768) f
    ushort* fg    = (ushort*)ws;                 // [0 .. 4,194,304) f
    float* ycomp  = ws + 4194304;                // -> ends 12,451,840
    float* s_all  = ws + 34080768;               // -> ends 34,998,272
    ushort* relu1t = (ushort*)(ws + 34998272);   // 4,194,304 us = 2,097,152 f
    ushort* wpack = (ushort*)(ws + 39192576);    // 368,640 us -> ends 39,376,896 f
    ushort* wpb   = (ushort*)(ws + 39376896);    // 258,048 us -> ends 39,505,920 f
    ushort* wpc1  = (ushort*)(ws + 39505920);    // 82,944 us -> ends 39,547,392 f
    ushort* xt    = (ushort*)(ws + 39547392);    // 12,582,912 us -> ends 45,838,848 f
    ushort* wg    = (ushort*)(ws + 45838848);    // 16,384 us -> ends 45,847,040 f

    // 0) weight prepacks + x transpose
    prepack_w_kernel<<<dim3(180), dim3(256), 0, stream>>>(ar_w, wpack);
    prepack_wb_kernel<<<dim3(126), dim3(256), 0, stream>>>(ddct_w, wpb);
    prepack_w1_kernel<<<dim3(41), dim3(256), 0, stream>>>(conv_w, dw1_w, wpc1);
    prepack_wg_kernel<<<dim3(8), dim3(256), 0, stream>>>(dw3_w, wg);
    xpose_kernel<<<dim3(BB * HW / 256), dim3(256), 0, stream>>>(x, xt);

    // 1) fused conv1 (fg NHWC bf16, gelu) + dw1 (relu1t NHWC-32 bf16, relu)
    conv1dw1_mfma_kernel<<<dim3(BB * HH * 2), dim3(256), 0, stream>>>(
        xt, wpc1, conv_b, dw1_b, fg, relu1t);

    // 2) branch convs (7 layers) as MFMA implicit GEMM on compact grid
    branch_mfma_kernel<<<dim3(7 * BB * 72), dim3(256), 0, stream>>>(
        fg, wpb, ddct_b, ycomp);

    // 3) depthwise stride-8 convs
    dctc_kernel<<<dim3((7 * BB * 64 * 32 * 32) / 256), dim3(256), 0, stream>>>(
        ycomp, dctc_w, dctc_b, s_all);

    // 3b) zero gated halo (after fg/ycomp are dead)
    halo_zero_kernel<<<dim3(514), dim3(256), 0, stream>>>(gated_t);

    // 4) gated (padded NHWC bf16) via MFMA gate conv + fused epilogue
    gated_mfma_kernel<<<dim3(BB * HH * 4), dim3(256), 0, stream>>>(
        relu1t, wg, dw3_b, s_all, gated_t);

    // 5) out = conv3x3(gated, ar_w)  512 -> 72, MFMA implicit GEMM
    //    (cb-outer + LDS weights + 2-deep B prefetch + T14 + setprio)
    conv_ar_mfma_kernel<<<dim3(BB * HH), dim3(256), 0, stream>>>(
        gated_t, wpack, ar_b, out);
}

// Round 27
// 338.794 us; speedup vs baseline: 1.0250x; 1.0250x over previous
//
#include <hip/hip_runtime.h>
#include <hip/hip_bf16.h>

#define BB 2
#define HH 256
#define WW 256
#define HW (HH*WW)
#define GP 258              // padded gated dim (1px halo each side)
#define GPP (GP*GP)

typedef __attribute__((ext_vector_type(8))) short bf16x8;
typedef __attribute__((ext_vector_type(4))) float f32x4;

__device__ __forceinline__ float geluf(float x) {
    return 0.5f * x * (1.0f + erff(x * 0.7071067811865475f));
}

__device__ __forceinline__ ushort f2bf(float f) {
    __hip_bfloat16 h = __float2bfloat16(f);
    return *reinterpret_cast<ushort*>(&h);
}
__device__ __forceinline__ float bf2f(ushort u) {
    uint v = ((uint)u) << 16;
    return *reinterpret_cast<float*>(&v);
}

// compact index [0,96) -> actual coordinate (rows/cols = 0,2,6 mod 8)
__device__ __forceinline__ int dec96(int i) {
    int q = i / 3, r = i - q * 3;
    return q * 8 + (r == 0 ? 0 : (r == 1 ? 2 : 6));
}

// x (NCHW fp32, 72ch) -> xt (NHWC bf16, 96ch zero-padded).
__global__ __launch_bounds__(256) void xpose_kernel(
    const float* __restrict__ x, ushort* __restrict__ xt)
{
    const int pix = blockIdx.x * 256 + threadIdx.x;   // [0, BB*HW)
    const int b   = pix >> 16;
    const int rem = pix & 65535;

    uint w[48];
    const float* xb = x + (size_t)b * 72 * HW + rem;
    #pragma unroll
    for (int i = 0; i < 36; ++i) {
        const ushort lo = f2bf(xb[(size_t)(2 * i)     * HW]);
        const ushort hi = f2bf(xb[(size_t)(2 * i + 1) * HW]);
        w[i] = (uint)lo | ((uint)hi << 16);
    }
    #pragma unroll
    for (int i = 36; i < 48; ++i) w[i] = 0;

    uint* dst = reinterpret_cast<uint*>(xt + (size_t)pix * 96);
    #pragma unroll
    for (int k = 0; k < 12; ++k) {
        uint4 u = { w[4*k], w[4*k+1], w[4*k+2], w[4*k+3] };
        *reinterpret_cast<uint4*>(dst + 4 * k) = u;
    }
}

// Prepack fused conv1(64co)+dw1(32co) weights into MFMA A-frag order.
__global__ __launch_bounds__(256) void prepack_w1_kernel(
    const float* __restrict__ conv_w, const float* __restrict__ dw1_w,
    ushort* __restrict__ wpc1)
{
    const int idx = blockIdx.x * 256 + threadIdx.x;   // 9*3*6*64 = 10368
    if (idx >= 9 * 3 * 6 * 64) return;
    const int lane = idx & 63;
    int rest = idx >> 6;
    const int mf = rest % 6; rest /= 6;
    const int cb = rest % 3;
    const int t  = rest / 3;
    const int co  = mf * 16 + (lane & 15);
    const int ci0 = cb * 32 + (lane >> 4) * 8;
    ushort* dst = wpc1 + (size_t)idx * 8;
    #pragma unroll
    for (int j = 0; j < 8; ++j) {
        const int ci = ci0 + j;
        float w = 0.0f;
        if (ci < 72)
            w = (co < 64) ? conv_w[((size_t)co * 72 + ci) * 9 + t]
                          : dw1_w[((size_t)(co - 64) * 72 + ci) * 9 + t];
        dst[j] = f2bf(w);
    }
}

// Fused conv1+dw1 as MFMA implicit GEMM (M=96, K=9*96) over xt.
// relu1 emitted as bf16 NHWC-32 (for the MFMA gate conv).
__global__ __launch_bounds__(256) void conv1dw1_mfma_kernel(
    const ushort* __restrict__ xt, const ushort* __restrict__ wpc1,
    const float* __restrict__ conv_b, const float* __restrict__ dw1_b,
    ushort* __restrict__ fg, ushort* __restrict__ relu1t)
{
    const int lane = threadIdx.x & 63;
    const int wave = threadIdx.x >> 6;
    const int l15  = lane & 15;
    const int lg   = lane >> 4;

    const int bid  = blockIdx.x;          // 1024 = b(2) * y(256) * half(2)
    const int b    = bid >> 9;
    const int rest = bid & 511;
    const int y    = rest >> 1;
    const int x0   = (rest & 1) * 128 + wave * 32;

    f32x4 acc[6][2];
    #pragma unroll
    for (int mf = 0; mf < 6; ++mf)
        #pragma unroll
        for (int nf = 0; nf < 2; ++nf)
            acc[mf][nf] = (f32x4){0.f, 0.f, 0.f, 0.f};

    const bf16x8 zero8 = {};

    #pragma unroll 1
    for (int t = 0; t < 9; ++t) {
        const int dy = t / 3 - 1, dx = t % 3 - 1;
        const int yy = y + dy;
        if ((unsigned)yy >= (unsigned)HH) continue;

        const int xA = x0 + l15 + dx;
        const int xB = xA + 16;
        const bool va = (unsigned)xA < (unsigned)WW;
        const bool vb = (unsigned)xB < (unsigned)WW;
        const int xAc = min(max(xA, 0), WW - 1);
        const int xBc = min(xB, WW - 1);

        const ushort* rowbase = xt + ((size_t)(b * HH + yy) * WW) * 96;
        const ushort* pA = rowbase + (size_t)xAc * 96 + lg * 8;
        const ushort* pB = rowbase + (size_t)xBc * 96 + lg * 8;
        const ushort* wp = wpc1 + (size_t)(t * 3) * (6 * 512) + lane * 8;

        #pragma unroll
        for (int cb = 0; cb < 3; ++cb) {
            bf16x8 B0 = *reinterpret_cast<const bf16x8*>(pA + cb * 32);
            bf16x8 B1 = *reinterpret_cast<const bf16x8*>(pB + cb * 32);
            B0 = va ? B0 : zero8;
            B1 = vb ? B1 : zero8;
            const ushort* wpc = wp + (size_t)cb * (6 * 512);
            #pragma unroll
            for (int mf = 0; mf < 6; ++mf) {
                const bf16x8 A = *reinterpret_cast<const bf16x8*>(wpc + mf * 512);
                acc[mf][0] = __builtin_amdgcn_mfma_f32_16x16x32_bf16(A, B0, acc[mf][0], 0, 0, 0);
                acc[mf][1] = __builtin_amdgcn_mfma_f32_16x16x32_bf16(A, B1, acc[mf][1], 0, 0, 0);
            }
        }
    }

    #pragma unroll
    for (int nf = 0; nf < 2; ++nf) {
        const int xx = x0 + nf * 16 + l15;
        ushort* fgp = fg + ((size_t)(b * HH + y) * WW + xx) * 64;
        #pragma unroll
        for (int mf = 0; mf < 4; ++mf) {
            const int co = mf * 16 + lg * 4;
            ushort pk[4];
            #pragma unroll
            for (int r = 0; r < 4; ++r)
                pk[r] = f2bf(geluf(acc[mf][nf][r] + conv_b[co + r]));
            *reinterpret_cast<uint2*>(fgp + co) = *reinterpret_cast<uint2*>(pk);
        }
    }
    // relu1t epilogue: bf16 NHWC-32
    #pragma unroll
    for (int mf = 4; mf < 6; ++mf) {
        const int co = (mf - 4) * 16 + lg * 4;
        #pragma unroll
        for (int nf = 0; nf < 2; ++nf) {
            const int xx = x0 + nf * 16 + l15;
            ushort pk[4];
            #pragma unroll
            for (int r = 0; r < 4; ++r)
                pk[r] = f2bf(fmaxf(acc[mf][nf][r] + dw1_b[co + r], 0.0f));
            *reinterpret_cast<uint2*>(relu1t + ((size_t)(b * HH + y) * WW + xx) * 32 + co) =
                *reinterpret_cast<uint2*>(pk);
        }
    }
}

// Prepack ddct weights (7 layers) into MFMA A-fragment order.
__global__ __launch_bounds__(256) void prepack_wb_kernel(
    const float* __restrict__ ddct_w, ushort* __restrict__ wpb)
{
    const int idx = blockIdx.x * 256 + threadIdx.x;   // 7*9*2*4*64 = 32256
    if (idx >= 7 * 9 * 2 * 4 * 64) return;
    const int lane = idx & 63;
    int rest = idx >> 6;
    const int mf = rest & 3; rest >>= 2;
    const int cb = rest & 1; rest >>= 1;
    const int t  = rest % 9;
    const int li = rest / 9;
    const int co  = mf * 16 + (lane & 15);
    const int ci0 = cb * 32 + (lane >> 4) * 8;
    ushort* dst = wpb + (size_t)idx * 8;
    #pragma unroll
    for (int j = 0; j < 8; ++j)
        dst[j] = f2bf(ddct_w[(((size_t)li * 64 + co) * 64 + ci0 + j) * 9 + t]);
}

// All 7 branch convs on the compact 96x96 grid as MFMA implicit GEMM.
__global__ __launch_bounds__(256) void branch_mfma_kernel(
    const ushort* __restrict__ fg, const ushort* __restrict__ wpb,
    const float* __restrict__ ddct_b, float* __restrict__ ycomp)
{
    const int lane = threadIdx.x & 63;
    const int wave = threadIdx.x >> 6;
    const int l15  = lane & 15;
    const int lg   = lane >> 4;

    int bid = blockIdx.x;              // (li*BB+b)*72 + t72
    const int t72 = bid % 72; bid /= 72;
    const int b  = bid & 1;
    const int li = bid >> 1;
    const int widx = t72 * 4 + wave;
    const int r  = widx / 3;
    const int c0 = (widx - r * 3) * 32;
    const int R  = dec96(r);

    const int cA = c0 + l15, cB = cA + 16;
    const int CA = dec96(cA), CB2 = dec96(cB);

    f32x4 acc[4][2];
    #pragma unroll
    for (int mf = 0; mf < 4; ++mf)
        #pragma unroll
        for (int nf = 0; nf < 2; ++nf)
            acc[mf][nf] = (f32x4){0.f, 0.f, 0.f, 0.f};

    const bf16x8 zero8 = {};
    const ushort* fgb = fg + (size_t)b * HW * 64;

    #pragma unroll 1
    for (int t = 0; t < 9; ++t) {
        const int dy = t / 3 - 1, dx = t % 3 - 1;
        const int yy = R + dy;
        if ((unsigned)yy >= (unsigned)HH) continue;

        const int xA = CA + dx, xB = CB2 + dx;
        const bool va = (unsigned)xA < (unsigned)WW;
        const bool vb = (unsigned)xB < (unsigned)WW;
        const int xAc = min(max(xA, 0), WW - 1);
        const int xBc = min(max(xB, 0), WW - 1);

        const ushort* rowb = fgb + (size_t)yy * WW * 64;
        const ushort* pA = rowb + (size_t)xAc * 64 + lg * 8;
        const ushort* pB = rowb + (size_t)xBc * 64 + lg * 8;
        const ushort* wp = wpb + (size_t)((li * 9 + t) * 2) * (4 * 512) + lane * 8;

        #pragma unroll
        for (int cb = 0; cb < 2; ++cb) {
            bf16x8 B0 = *reinterpret_cast<const bf16x8*>(pA + cb * 32);
            bf16x8 B1 = *reinterpret_cast<const bf16x8*>(pB + cb * 32);
            B0 = va ? B0 : zero8;
            B1 = vb ? B1 : zero8;
            const ushort* wpc = wp + (size_t)cb * (4 * 512);
            #pragma unroll
            for (int mf = 0; mf < 4; ++mf) {
                const bf16x8 A = *reinterpret_cast<const bf16x8*>(wpc + mf * 512);
                acc[mf][0] = __builtin_amdgcn_mfma_f32_16x16x32_bf16(A, B0, acc[mf][0], 0, 0, 0);
                acc[mf][1] = __builtin_amdgcn_mfma_f32_16x16x32_bf16(A, B1, acc[mf][1], 0, 0, 0);
            }
        }
    }

    #pragma unroll
    for (int nf = 0; nf < 2; ++nf) {
        const int c = c0 + nf * 16 + l15;
        const int C = dec96(c);
        const ushort* res = fgb + ((size_t)R * WW + C) * 64;
        #pragma unroll
        for (int mf = 0; mf < 4; ++mf) {
            const int co = mf * 16 + lg * 4;
            ushort r4[4];
            *reinterpret_cast<uint2*>(r4) = *reinterpret_cast<const uint2*>(res + co);
            #pragma unroll
            for (int rr = 0; rr < 4; ++rr) {
                const float v = geluf(acc[mf][nf][rr] + ddct_b[li * 64 + co + rr]) + bf2f(r4[rr]);
                ycomp[((((size_t)li * BB + b) * 64 + co + rr) * 96 + r) * 96 + c] = v;
            }
        }
    }
}

// Depthwise 3x3 stride 8 dil 2 pad 2 -> 32x32 (DCT->IDCT identity skipped).
__global__ __launch_bounds__(256) void dctc_kernel(
    const float* __restrict__ ycomp, const float* __restrict__ dctc_w,
    const float* __restrict__ dctc_b, float* __restrict__ s_all)
{
    const int idx = blockIdx.x * 256 + threadIdx.x;
    if (idx >= 7 * BB * 64 * 32 * 32) return;
    const int ow = idx & 31;
    const int oh = (idx >> 5) & 31;
    const int c  = (idx >> 10) & 63;
    const int b  = (idx >> 16) & (BB - 1);
    const int li = idx >> 17;

    const float* yc = ycomp + (((size_t)li * BB + b) * 64 + c) * (96 * 96);
    const float* w  = dctc_w + (li * 64 + c) * 9;
    float acc = dctc_b[li * 64 + c];
    #pragma unroll
    for (int ky = 0; ky < 3; ++ky) {
        const int cr = 3 * oh + ky - 1;
        if (cr < 0) continue;
        #pragma unroll
        for (int kx = 0; kx < 3; ++kx) {
            const int cc = 3 * ow + kx - 1;
            if (cc < 0) continue;
            acc = fmaf(yc[cr * 96 + cc], w[ky * 3 + kx], acc);
        }
    }
    s_all[idx] = acc;
}

// Prepack gate weights into MFMA A-frag order:
// wg[(ct*64+lane)*8+j] = dw3_w[ch=ct*16+(lane&15)][k=(lane>>4)*8+j]
__global__ __launch_bounds__(256) void prepack_wg_kernel(
    const float* __restrict__ dw3_w, ushort* __restrict__ wg)
{
    const int idx = blockIdx.x * 256 + threadIdx.x;   // 32*64 = 2048
    if (idx >= 2048) return;
    const int lane = idx & 63;
    const int ct = idx >> 6;
    const int ch = ct * 16 + (lane & 15);
    const int k0 = (lane >> 4) * 8;
    ushort* dst = wg + (size_t)idx * 8;
    #pragma unroll
    for (int j = 0; j < 8; ++j)
        dst[j] = f2bf(dw3_w[(size_t)ch * 32 + k0 + j]);
}

// Zero the 1px halo border of the padded gated tensor.
// Must run AFTER fg/ycomp (aliasing the padded gated region) are dead.
__global__ __launch_bounds__(256) void halo_zero_kernel(ushort* __restrict__ gt)
{
    const int PB = 2 * GP * 64 + 2 * 256 * 64;   // 65792 uint4 per batch
    const int i = blockIdx.x * 256 + threadIdx.x;
    if (i >= BB * PB) return;
    const int b = i / PB;
    int r = i - b * PB;
    size_t px;
    int c4;
    if (r < 2 * GP * 64) {
        const int rr = r / (GP * 64);
        int rem = r - rr * (GP * 64);
        const int xp = rem / 64; c4 = rem % 64;
        px = (size_t)(rr ? GP - 1 : 0) * GP + xp;
    } else {
        r -= 2 * GP * 64;
        const int side = r / (256 * 64);
        int rem = r - side * (256 * 64);
        const int yp = 1 + rem / 64; c4 = rem % 64;
        px = (size_t)yp * GP + (side ? GP - 1 : 0);
    }
    const uint4 z = {0u, 0u, 0u, 0u};
    *reinterpret_cast<uint4*>(gt + ((size_t)b * GPP + px) * 512 + c4 * 8) = z;
}

// Gate 1x1 conv (32->512) on MFMA (K=32 = one mfma_16x16x32), fused with
// sigmoid + bilinear upsample + multiply, writing PADDED NHWC bf16.
__global__ __launch_bounds__(256, 2) void gated_mfma_kernel(
    const ushort* __restrict__ relu1t, const ushort* __restrict__ wg,
    const float* __restrict__ dw3_b, const float* __restrict__ s_all,
    ushort* __restrict__ gt)
{
    __shared__ float nodes[5120];        // [512 ch][10 x-nodes], y-blended
    const int tid  = threadIdx.x;
    const int lane = tid & 63;
    const int wave = tid >> 6;
    const int l15  = lane & 15;
    const int lg   = lane >> 4;

    const int bid = blockIdx.x;          // 2048 = b(2) * y(256) * xq(4)
    const int b  = bid >> 10;
    const int y  = (bid >> 2) & 255;
    const int x0 = (bid & 3) * 64;

    const float sy = (y + 0.5f) * 0.125f - 0.5f;
    const float fy0f = floorf(sy);
    const float fy = sy - fy0f;
    int y0 = (int)fy0f;
    const int y1 = min(y0 + 1, 31);
    y0 = max(y0, 0);
    const int xb = (x0 >> 3) - 1;

    const int lmap[8] = {0, 1, 2, 3, 4, 3, 5, 6};
    #pragma unroll 1
    for (int e = tid; e < 5120; e += 256) {
        const int ch = e / 10, j = e - ch * 10;
        const int li = lmap[ch >> 6];
        const float* sp = s_all + (((size_t)li * BB + b) * 64 + (ch & 63)) * 1024;
        const int xn = min(max(xb + j, 0), 31);
        const float a0 = sp[y0 * 32 + xn], a1 = sp[y1 * 32 + xn];
        nodes[e] = a0 + fy * (a1 - a0);
    }
    __syncthreads();

    // B fragments: 4 px-tiles; K=32 contiguous per px in relu1t
    bf16x8 Bv[4];
    const ushort* rb = relu1t + ((size_t)(b * HH + y) * WW + x0) * 32;
    #pragma unroll
    for (int pxt = 0; pxt < 4; ++pxt)
        Bv[pxt] = *reinterpret_cast<const bf16x8*>(rb + (pxt * 16 + l15) * 32 + lg * 8);

    ushort* gy = gt + (((size_t)b * GPP) + (size_t)(y + 1) * GP + (x0 + 1)) * 512;
    const f32x4 zero4 = {0.f, 0.f, 0.f, 0.f};

    #pragma unroll 1
    for (int i = 0; i < 8; ++i) {
        const int ct = wave * 8 + i;
        const bf16x8 A = *reinterpret_cast<const bf16x8*>(wg + (size_t)(ct * 64 + lane) * 8);
        const int ch0 = ct * 16 + lg * 4;
        const float4 bb = *reinterpret_cast<const float4*>(dw3_b + ch0);
        const float bias4[4] = {bb.x, bb.y, bb.z, bb.w};
        f32x4 acc[4];
        #pragma unroll
        for (int pxt = 0; pxt < 4; ++pxt)
            acc[pxt] = __builtin_amdgcn_mfma_f32_16x16x32_bf16(A, Bv[pxt], zero4, 0, 0, 0);
        #pragma unroll
        for (int pxt = 0; pxt < 4; ++pxt) {
            const int pxl = pxt * 16 + l15;
            const int jl = (pxl + 4) >> 3;
            const float fx = (float)((pxl + 4) & 7) * 0.125f + 0.0625f;
            ushort pk[4];
            #pragma unroll
            for (int r = 0; r < 4; ++r) {
                const int ch = ch0 + r;
                const float g = 1.0f / (1.0f + exp2f(-1.4426950408889634f * (acc[pxt][r] + bias4[r])));
                const float n0v = nodes[ch * 10 + jl];
                const float n1v = nodes[ch * 10 + jl + 1];
                const float v = n0v + fx * (n1v - n0v);
                pk[r] = f2bf(v * g);
            }
            *reinterpret_cast<uint2*>(gy + (size_t)pxl * 512 + ch0) = *reinterpret_cast<uint2*>(pk);
        }
    }
}

// Prepack ar_w into MFMA A-fragment order (bf16), CB-MAJOR for LDS staging:
// wpack[(((cb*9 + t)*5 + mf)*64 + lane)*8 + j]
__global__ __launch_bounds__(256) void prepack_w_kernel(
    const float* __restrict__ ar_w, ushort* __restrict__ wpack)
{
    const int idx = blockIdx.x * 256 + threadIdx.x;   // 16*9*5*64 = 46080
    if (idx >= 16 * 9 * 5 * 64) return;
    const int lane = idx & 63;
    int rest = idx >> 6;
    const int mf = rest % 5; rest /= 5;
    const int t  = rest % 9;
    const int cb = rest / 9;
    const int co  = mf * 16 + (lane & 15);
    const int ci0 = cb * 32 + (lane >> 4) * 8;
    ushort* dst = wpack + (size_t)idx * 8;
    #pragma unroll
    for (int j = 0; j < 8; ++j) {
        const float w = (co < 72) ? ar_w[((size_t)co * 512 + ci0 + j) * 9 + t] : 0.0f;
        dst[j] = f2bf(w);
    }
}

#define WPK_CHUNK (9 * 5 * 512)   // ushorts per cb chunk = 23040 (46080 B)

// Final conv 512->72 as implicit GEMM on MFMA (padded NHWC bf16 input).
// v9 (measured best, ~169us): cb-outer, 46KB LDS weights, B tap-prefetch,
// T14 stage split, setprio. Ten structural variants (v2-v10) confirmed
// this as the plateau of the cb-phase barrier schedule.
__global__ __launch_bounds__(256, 2) void conv_ar_mfma_kernel(
    const ushort* __restrict__ gt, const ushort* __restrict__ wpack,
    const float* __restrict__ ar_b, float* __restrict__ out)
{
    __shared__ ushort smw[WPK_CHUNK];
    const int tid  = threadIdx.x;
    const int lane = tid & 63;
    const int wave = tid >> 6;
    const int l15  = lane & 15;
    const int lg   = lane >> 4;

    // bijective XCD swizzle: nwg=512, 8 XCDs, 64 logical blocks per XCD
    const int lb = (blockIdx.x & 7) * 64 + (blockIdx.x >> 3);
    const int b  = lb >> 8;
    const int y  = lb & 255;
    const int x0 = wave * 64;

    f32x4 acc[5][4];
    #pragma unroll
    for (int mf = 0; mf < 5; ++mf)
        #pragma unroll
        for (int nf = 0; nf < 4; ++nf)
            acc[mf][nf] = (f32x4){0.f, 0.f, 0.f, 0.f};

    const ushort* rowp[3];
    #pragma unroll
    for (int dy = 0; dy < 3; ++dy)
        rowp[dy] = gt + ((size_t)b * GPP + (size_t)(y + dy) * GP) * 512;
    int off[3][4];
    #pragma unroll
    for (int dx = 0; dx < 3; ++dx)
        #pragma unroll
        for (int nf = 0; nf < 4; ++nf)
            off[dx][nf] = (x0 + nf * 16 + l15 + dx) * 512 + lg * 8;

    // prologue: stage cb=0 into LDS
    uint4 streg[12];
    {
        const uint4* s = reinterpret_cast<const uint4*>(wpack);
        #pragma unroll
        for (int i = 0; i < 12; ++i) {
            const int e = i * 256 + tid;
            streg[i] = (e < 2880) ? s[e] : (uint4){0u, 0u, 0u, 0u};
        }
        uint4* d = reinterpret_cast<uint4*>(smw);
        #pragma unroll
        for (int i = 0; i < 12; ++i) {
            const int e = i * 256 + tid;
            if (e < 2880) d[e] = streg[i];
        }
    }
    __syncthreads();

    #pragma unroll 1
    for (int cb = 0; cb < 16; ++cb) {
        // T14: issue next cb's stage loads now; latency hides under MFMAs
        if (cb < 15) {
            const uint4* s = reinterpret_cast<const uint4*>(
                wpack + (size_t)(cb + 1) * WPK_CHUNK);
            #pragma unroll
            for (int i = 0; i < 12; ++i) {
                const int e = i * 256 + tid;
                if (e < 2880) streg[i] = s[e];
            }
        }

        const int cbo = cb * 32;
        // B double-buffer across taps (static indices, full unroll)
        bf16x8 Bcur[4], Bnxt[4];
        #pragma unroll
        for (int nf = 0; nf < 4; ++nf)
            Bcur[nf] = *reinterpret_cast<const bf16x8*>(rowp[0] + off[0][nf] + cbo);

        #pragma unroll
        for (int t = 0; t < 9; ++t) {
            if (t < 8) {
                const int dyn = (t + 1) / 3, dxn = (t + 1) % 3;
                #pragma unroll
                for (int nf = 0; nf < 4; ++nf)
                    Bnxt[nf] = *reinterpret_cast<const bf16x8*>(
                        rowp[dyn] + off[dxn][nf] + cbo);
            }
            __builtin_amdgcn_s_setprio(1);          // T5: favor MFMA cluster
            #pragma unroll
            for (int mf = 0; mf < 5; ++mf) {
                const bf16x8 A = *reinterpret_cast<const bf16x8*>(
                    smw + (t * 5 + mf) * 512 + lane * 8);
                #pragma unroll
                for (int nf = 0; nf < 4; ++nf)
                    acc[mf][nf] = __builtin_amdgcn_mfma_f32_16x16x32_bf16(
                        A, Bcur[nf], acc[mf][nf], 0, 0, 0);
            }
            __builtin_amdgcn_s_setprio(0);
            if (t < 8) {
                #pragma unroll
                for (int nf = 0; nf < 4; ++nf) Bcur[nf] = Bnxt[nf];
            }
        }

        __syncthreads();           // all waves done reading smw for this cb
        if (cb < 15) {
            uint4* d = reinterpret_cast<uint4*>(smw);
            #pragma unroll
            for (int i = 0; i < 12; ++i) {
                const int e = i * 256 + tid;
                if (e < 2880) d[e] = streg[i];
            }
        }
        __syncthreads();           // next stage visible
    }

    #pragma unroll
    for (int mf = 0; mf < 5; ++mf) {
        const int co = mf * 16 + lg * 4;
        if (co >= 72) continue;
        #pragma unroll
        for (int nf = 0; nf < 4; ++nf) {
            const int x = x0 + nf * 16 + l15;
            float* op = out + (((size_t)(b * 72 + co) * HH + y) * WW) + x;
            #pragma unroll
            for (int r = 0; r < 4; ++r)
                op[(size_t)r * HW] = acc[mf][nf][r] + ar_b[co + r];
        }
    }
}

extern "C" void kernel_launch(void* const* d_in, const int* in_sizes, int n_in,
                              void* d_out, int out_size, void* d_ws, size_t ws_size,
                              hipStream_t stream) {
    const float* x      = (const float*)d_in[0];
    const float* conv_w = (const float*)d_in[1];
    const float* conv_b = (const float*)d_in[2];
    const float* ddct_w = (const float*)d_in[3];
    const float* ddct_b = (const float*)d_in[4];
    const float* dctc_w = (const float*)d_in[5];
    const float* dctc_b = (const float*)d_in[6];
    const float* dw1_w  = (const float*)d_in[7];
    const float* dw1_b  = (const float*)d_in[8];
    const float* dw3_w  = (const float*)d_in[9];
    const float* dw3_b  = (const float*)d_in[10];
    const float* ar_w   = (const float*)d_in[11];
    const float* ar_b   = (const float*)d_in[12];
    float* out = (float*)d_out;

    float* ws = (float*)d_ws;
    // Layout (float slots). gated (padded) spans [0 .. 34,080,768); fg/ycomp
    // alias it (both dead before halo+gated writes — halo_zero runs AFTER dctc).
    ushort* gated_t = (ushort*)ws;               // [0 .. 34,080,768) f
    ushort* fg    = (ushort*)ws;                 // [0 .. 4,194,304) f
    float* ycomp  = ws + 4194304;                // -> ends 12,451,840
    float* s_all  = ws + 34080768;               // -> ends 34,998,272
    ushort* relu1t = (ushort*)(ws + 34998272);   // 4,194,304 us = 2,097,152 f
    ushort* wpack = (ushort*)(ws + 39192576);    // 368,640 us -> ends 39,376,896 f
    ushort* wpb   = (ushort*)(ws + 39376896);    // 258,048 us -> ends 39,505,920 f
    ushort* wpc1  = (ushort*)(ws + 39505920);    // 82,944 us -> ends 39,547,392 f
    ushort* xt    = (ushort*)(ws + 39547392);    // 12,582,912 us -> ends 45,838,848 f
    ushort* wg    = (ushort*)(ws + 45838848);    // 16,384 us -> ends 45,847,040 f

    // 0) weight prepacks + x transpose
    prepack_w_kernel<<<dim3(180), dim3(256), 0, stream>>>(ar_w, wpack);
    prepack_wb_kernel<<<dim3(126), dim3(256), 0, stream>>>(ddct_w, wpb);
    prepack_w1_kernel<<<dim3(41), dim3(256), 0, stream>>>(conv_w, dw1_w, wpc1);
    prepack_wg_kernel<<<dim3(8), dim3(256), 0, stream>>>(dw3_w, wg);
    xpose_kernel<<<dim3(BB * HW / 256), dim3(256), 0, stream>>>(x, xt);

    // 1) fused conv1 (fg NHWC bf16, gelu) + dw1 (relu1t NHWC-32 bf16, relu)
    conv1dw1_mfma_kernel<<<dim3(BB * HH * 2), dim3(256), 0, stream>>>(
        xt, wpc1, conv_b, dw1_b, fg, relu1t);

    // 2) branch convs (7 layers) as MFMA implicit GEMM on compact grid
    branch_mfma_kernel<<<dim3(7 * BB * 72), dim3(256), 0, stream>>>(
        fg, wpb, ddct_b, ycomp);

    // 3) depthwise stride-8 convs
    dctc_kernel<<<dim3((7 * BB * 64 * 32 * 32) / 256), dim3(256), 0, stream>>>(
        ycomp, dctc_w, dctc_b, s_all);

    // 3b) zero gated halo (after fg/ycomp are dead)
    halo_zero_kernel<<<dim3(514), dim3(256), 0, stream>>>(gated_t);

    // 4) gated (padded NHWC bf16) via MFMA gate conv + fused epilogue
    gated_mfma_kernel<<<dim3(BB * HH * 4), dim3(256), 0, stream>>>(
        relu1t, wg, dw3_b, s_all, gated_t);

    // 5) out = conv3x3(gated, ar_w)  512 -> 72, MFMA implicit GEMM
    //    (cb-outer + LDS weights + B/stage prefetch + setprio)
    conv_ar_mfma_kernel<<<dim3(BB * HH), dim3(256), 0, stream>>>(
        gated_t, wpack, ar_b, out);
}